// Round 1
// baseline (874.012 us; speedup 1.0000x reference)
//
#include <hip/hip_runtime.h>
#include <math.h>

// Problem constants
// B=512, H=W=14, DIN=512, EDIM=64, K=256, GRID=2 -> 2048 tokens, 128 hidden
#define N_TOKENS   2048
#define DECODED_SZ 51380224   // 512*14*14*512
// d_out layout: [decoded (51380224)][perplexity (1)][commitment (1)][indices (2048)]

__device__ __forceinline__ float gelu_exact(float x) {
    return 0.5f * x * (1.0f + erff(x * 0.70710678118654752440f));
}

// ---------------------------------------------------------------------------
// K1: pooled_h[token][128] = mean_{49 pos} gelu(delta @ enc_w1 + b1)
// One block (128 thr) per token. K chunked by 64 into LDS.
// Thread tile: TM=7 positions (m-group g=t>>4), TN=8 channels split as
// {4*ng..+3} and {64+4*ng..+3} (ng=t&15) to keep ds_read_b128 conflict-free.
// ---------------------------------------------------------------------------
__global__ __launch_bounds__(128) void k1_enc_pool(
    const float* __restrict__ t0, const float* __restrict__ t1,
    const float* __restrict__ w1, const float* __restrict__ b1,
    float* __restrict__ pooled)
{
    __shared__ float sW[64 * 128];     // w1 chunk [k][n], 32 KB
    __shared__ float sD[49 * 68];      // delta chunk [m][k], stride 68, 13.3 KB

    const int t  = threadIdx.x;
    const int tk = blockIdx.x;
    const int b  = tk >> 2;
    const int gy = (tk >> 1) & 1;
    const int gx = tk & 1;

    const int ng = t & 15;     // channel group
    const int g  = t >> 4;     // position group (0..7; g=7 is padding, idle)

    const float4* __restrict__ w1v = reinterpret_cast<const float4*>(w1);
    const float4* __restrict__ t0v = reinterpret_cast<const float4*>(t0);
    const float4* __restrict__ t1v = reinterpret_cast<const float4*>(t1);

    // Per-thread delta-row pointers (clamped for the padding group)
    const float* rowp[7];
#pragma unroll
    for (int mm = 0; mm < 7; ++mm) {
        int m = g * 7 + mm;
        if (m > 48) m = 48;
        rowp[mm] = sD + m * 68;
    }

    float acc[7][8] = {};

    for (int kc = 0; kc < 8; ++kc) {
        // stage w1 chunk: 64x128 floats = 2048 float4
#pragma unroll
        for (int i = 0; i < 16; ++i) {
            int idx4 = t + i * 128;
            reinterpret_cast<float4*>(sW)[idx4] = w1v[kc * 2048 + idx4];
        }
        // stage delta chunk: 49 rows x 16 float4
        for (int i = t; i < 49 * 16; i += 128) {
            int m = i >> 4, j = i & 15;
            int py = m / 7, px = m % 7;
            int gpos = ((b * 14 + 7 * gy + py) * 14 + 7 * gx + px) * 128 + kc * 16 + j;
            float4 a = t1v[gpos];
            float4 c = t0v[gpos];
            float4 d;
            d.x = a.x - c.x; d.y = a.y - c.y; d.z = a.z - c.z; d.w = a.w - c.w;
            reinterpret_cast<float4*>(sD + m * 68)[j] = d;
        }
        __syncthreads();

        for (int kk = 0; kk < 64; kk += 2) {
            const float* wr0 = sW + kk * 128;
            const float* wr1 = wr0 + 128;
            const float4 wa0 = *reinterpret_cast<const float4*>(wr0 + 4 * ng);
            const float4 wb0 = *reinterpret_cast<const float4*>(wr0 + 64 + 4 * ng);
            const float4 wa1 = *reinterpret_cast<const float4*>(wr1 + 4 * ng);
            const float4 wb1 = *reinterpret_cast<const float4*>(wr1 + 64 + 4 * ng);
#pragma unroll
            for (int mm = 0; mm < 7; ++mm) {
                const float2 dv = *reinterpret_cast<const float2*>(rowp[mm] + kk);
                float* A = acc[mm];
                A[0] = fmaf(dv.x, wa0.x, A[0]);
                A[1] = fmaf(dv.x, wa0.y, A[1]);
                A[2] = fmaf(dv.x, wa0.z, A[2]);
                A[3] = fmaf(dv.x, wa0.w, A[3]);
                A[4] = fmaf(dv.x, wb0.x, A[4]);
                A[5] = fmaf(dv.x, wb0.y, A[5]);
                A[6] = fmaf(dv.x, wb0.z, A[6]);
                A[7] = fmaf(dv.x, wb0.w, A[7]);
                A[0] = fmaf(dv.y, wa1.x, A[0]);
                A[1] = fmaf(dv.y, wa1.y, A[1]);
                A[2] = fmaf(dv.y, wa1.z, A[2]);
                A[3] = fmaf(dv.y, wa1.w, A[3]);
                A[4] = fmaf(dv.y, wb1.x, A[4]);
                A[5] = fmaf(dv.y, wb1.y, A[5]);
                A[6] = fmaf(dv.y, wb1.z, A[6]);
                A[7] = fmaf(dv.y, wb1.w, A[7]);
            }
        }
        __syncthreads();
    }

    // epilogue: bias + gelu + partial pool over this thread's positions
    const float4 ba = *reinterpret_cast<const float4*>(b1 + 4 * ng);
    const float4 bb = *reinterpret_cast<const float4*>(b1 + 64 + 4 * ng);
    float p[8] = {};
#pragma unroll
    for (int mm = 0; mm < 7; ++mm) {
        int m = g * 7 + mm;
        if (m < 49) {
            p[0] += gelu_exact(acc[mm][0] + ba.x);
            p[1] += gelu_exact(acc[mm][1] + ba.y);
            p[2] += gelu_exact(acc[mm][2] + ba.z);
            p[3] += gelu_exact(acc[mm][3] + ba.w);
            p[4] += gelu_exact(acc[mm][4] + bb.x);
            p[5] += gelu_exact(acc[mm][5] + bb.y);
            p[6] += gelu_exact(acc[mm][6] + bb.z);
            p[7] += gelu_exact(acc[mm][7] + bb.w);
        }
    }
    // reduce across the 8 position groups (reuse sW)
    float* sR = sW;
    float4 pa; pa.x = p[0]; pa.y = p[1]; pa.z = p[2]; pa.w = p[3];
    float4 pb; pb.x = p[4]; pb.y = p[5]; pb.z = p[6]; pb.w = p[7];
    *reinterpret_cast<float4*>(sR + g * 128 + 4 * ng)      = pa;
    *reinterpret_cast<float4*>(sR + g * 128 + 64 + 4 * ng) = pb;
    __syncthreads();
    if (t < 128) {
        float s = 0.f;
#pragma unroll
        for (int gg = 0; gg < 8; ++gg) s += sR[gg * 128 + t];
        pooled[tk * 128 + t] = s * (1.0f / 49.0f);
    }
}

// ---------------------------------------------------------------------------
// K2: per-token middle: e = pooled @ w2 + b2; VQ argmin; hist/commit atomics;
// decoder GEMMs -> dec[token][512] in ws. 64 blocks x 256 thr, 32 tokens/blk.
// ---------------------------------------------------------------------------
__global__ __launch_bounds__(256) void k2_mid(
    const float* __restrict__ pooled,
    const float* __restrict__ w2,  const float* __restrict__ b2,
    const float* __restrict__ cb,
    const float* __restrict__ dw1, const float* __restrict__ db1,
    const float* __restrict__ dw2, const float* __restrict__ db2,
    float* __restrict__ dec, float* __restrict__ hist, float* __restrict__ commit,
    float* __restrict__ out_idx)
{
    __shared__ float ph[32 * 128];   // pooled tokens
    __shared__ float es[32 * 64];    // encoded e
    __shared__ float qs[32 * 64];    // quantized q
    __shared__ float hd[32 * 128];   // decoder hidden
    __shared__ int   idxs[32];
    __shared__ float rd[256];
    __shared__ int   ri[256];

    const int t   = threadIdx.x;
    const int tk0 = blockIdx.x * 32;

    // load pooled tokens
    for (int i = t; i < 1024; i += 256)
        reinterpret_cast<float4*>(ph)[i] =
            reinterpret_cast<const float4*>(pooled + tk0 * 128)[i];
    __syncthreads();

    // e = ph @ w2 + b2   (j = t&63, 4 groups x 8 tokens)
    {
        const int j = t & 63, grp = t >> 6;
        float a[8];
        const float bj = b2[j];
#pragma unroll
        for (int q = 0; q < 8; ++q) a[q] = bj;
        for (int k = 0; k < 128; ++k) {
            const float wv = w2[k * 64 + j];
#pragma unroll
            for (int q = 0; q < 8; ++q)
                a[q] = fmaf(ph[(grp * 8 + q) * 128 + k], wv, a[q]);
        }
#pragma unroll
        for (int q = 0; q < 8; ++q) es[(grp * 8 + q) * 64 + j] = a[q];
    }
    __syncthreads();

    // VQ: 8 threads per token, 32 codes each (contiguous -> first-min tiebreak)
    {
        const int q8 = t & 7, tt = t >> 3;
        float dmin = 3.4e38f; int imin = 0;
        const float* e = es + tt * 64;
        for (int c = q8 * 32; c < q8 * 32 + 32; ++c) {
            const float* cr = cb + c * 64;
            float d = 0.f;
#pragma unroll 8
            for (int k = 0; k < 64; ++k) {
                float df = e[k] - cr[k];
                d = fmaf(df, df, d);
            }
            if (d < dmin) { dmin = d; imin = c; }
        }
        rd[t] = dmin; ri[t] = imin;
    }
    __syncthreads();
    if (t < 32) {
        float dm = rd[t * 8]; int im = ri[t * 8];
#pragma unroll
        for (int q = 1; q < 8; ++q) {
            float d = rd[t * 8 + q];
            int   i = ri[t * 8 + q];
            if (d < dm) { dm = d; im = i; }
        }
        idxs[t] = im;
        out_idx[tk0 + t] = (float)im;
        atomicAdd(&hist[im], 1.0f);
        atomicAdd(commit, dm);
    }
    __syncthreads();

    // gather quantized vectors
    for (int i = t; i < 32 * 64; i += 256) {
        int tt = i >> 6, k = i & 63;
        qs[i] = cb[idxs[tt] * 64 + k];
    }
    __syncthreads();

    // hd = gelu(q @ dw1 + db1)   (j = t&127, 2 halves x 16 tokens)
    {
        const int j = t & 127, half = t >> 7;
        float a[16];
        const float bj = db1[j];
#pragma unroll
        for (int q = 0; q < 16; ++q) a[q] = bj;
        for (int k = 0; k < 64; ++k) {
            const float wv = dw1[k * 128 + j];
#pragma unroll
            for (int q = 0; q < 16; ++q)
                a[q] = fmaf(qs[(half * 16 + q) * 64 + k], wv, a[q]);
        }
#pragma unroll
        for (int q = 0; q < 16; ++q) hd[(half * 16 + q) * 128 + j] = gelu_exact(a[q]);
    }
    __syncthreads();

    // dec = hd @ dw2 + db2  (each thread: cols t and t+256, 8-token tiles)
    {
        const float bb0 = db2[t], bb1 = db2[t + 256];
        for (int tg = 0; tg < 4; ++tg) {
            float a0[8], a1[8];
#pragma unroll
            for (int q = 0; q < 8; ++q) { a0[q] = bb0; a1[q] = bb1; }
            for (int j = 0; j < 128; ++j) {
                const float w0 = dw2[j * 512 + t];
                const float w1v = dw2[j * 512 + 256 + t];
#pragma unroll
                for (int q = 0; q < 8; ++q) {
                    const float h = hd[(tg * 8 + q) * 128 + j];
                    a0[q] = fmaf(h, w0, a0[q]);
                    a1[q] = fmaf(h, w1v, a1[q]);
                }
            }
#pragma unroll
            for (int q = 0; q < 8; ++q) {
                dec[(tk0 + tg * 8 + q) * 512 + t]       = a0[q];
                dec[(tk0 + tg * 8 + q) * 512 + 256 + t] = a1[q];
            }
        }
    }
}

// ---------------------------------------------------------------------------
// K2b: finalize perplexity + commitment (1 block)
// ---------------------------------------------------------------------------
__global__ __launch_bounds__(256) void k2b_final(
    const float* __restrict__ hist, const float* __restrict__ commit,
    float* __restrict__ out2)
{
    __shared__ float red[256];
    const int t = threadIdx.x;
    float p = hist[t] * (1.0f / 2048.0f);
    red[t] = p * logf(p + 1e-10f);
    __syncthreads();
    for (int s = 128; s > 0; s >>= 1) {
        if (t < s) red[t] += red[t + s];
        __syncthreads();
    }
    if (t == 0) {
        out2[0] = expf(-red[0]);
        out2[1] = commit[0] * (1.0f / 131072.0f);   // /(2048*64)
    }
}

// ---------------------------------------------------------------------------
// K3: bilinear upsample dec[B,2,2,512] -> decoded[B,14,14,512]
// half-pixel centers, edge clamp (== jax.image.resize bilinear for 2->14)
// one block per batch; dec row cached in LDS.
// ---------------------------------------------------------------------------
__global__ __launch_bounds__(256) void k3_upsample(
    const float* __restrict__ dec, float* __restrict__ out)
{
    __shared__ float sdec[4 * 512];
    const int b = blockIdx.x, t = threadIdx.x;
    for (int i = t; i < 512; i += 256)
        reinterpret_cast<float4*>(sdec)[i] =
            reinterpret_cast<const float4*>(dec + b * 2048)[i];
    __syncthreads();

    const float4* s4 = reinterpret_cast<const float4*>(sdec);
    float4* o4 = reinterpret_cast<float4*>(out) + b * 25088;

    for (int i = t; i < 25088; i += 256) {   // 196 positions x 128 float4
        const int c4 = i & 127;
        const int pos = i >> 7;
        const int x = pos % 14, y = pos / 14;

        const float sy = (y + 0.5f) * (1.0f / 7.0f) - 0.5f;
        const float sx = (x + 0.5f) * (1.0f / 7.0f) - 0.5f;
        const int iy = (int)floorf(sy), ix = (int)floorf(sx);
        const float fy = sy - (float)iy, fx = sx - (float)ix;
        const int y0 = min(max(iy, 0), 1),     y1 = min(max(iy + 1, 0), 1);
        const int x0 = min(max(ix, 0), 1),     x1 = min(max(ix + 1, 0), 1);

        const float4 v00 = s4[(y0 * 2 + x0) * 128 + c4];
        const float4 v01 = s4[(y0 * 2 + x1) * 128 + c4];
        const float4 v10 = s4[(y1 * 2 + x0) * 128 + c4];
        const float4 v11 = s4[(y1 * 2 + x1) * 128 + c4];

        const float w00 = (1.f - fy) * (1.f - fx), w01 = (1.f - fy) * fx;
        const float w10 = fy * (1.f - fx),         w11 = fy * fx;

        float4 r;
        r.x = w00 * v00.x + w01 * v01.x + w10 * v10.x + w11 * v11.x;
        r.y = w00 * v00.y + w01 * v01.y + w10 * v10.y + w11 * v11.y;
        r.z = w00 * v00.z + w01 * v01.z + w10 * v10.z + w11 * v11.z;
        r.w = w00 * v00.w + w01 * v01.w + w10 * v10.w + w11 * v11.w;
        o4[i] = r;
    }
}

// ---------------------------------------------------------------------------
extern "C" void kernel_launch(void* const* d_in, const int* in_sizes, int n_in,
                              void* d_out, int out_size, void* d_ws, size_t ws_size,
                              hipStream_t stream)
{
    const float* t0  = (const float*)d_in[0];
    const float* t1  = (const float*)d_in[1];
    const float* w1  = (const float*)d_in[2];
    const float* b1  = (const float*)d_in[3];
    const float* w2  = (const float*)d_in[4];
    const float* b2  = (const float*)d_in[5];
    const float* dw1 = (const float*)d_in[6];
    const float* db1 = (const float*)d_in[7];
    const float* dw2 = (const float*)d_in[8];
    const float* db2 = (const float*)d_in[9];
    const float* cb  = (const float*)d_in[10];

    float* out = (float*)d_out;
    float* ws  = (float*)d_ws;

    float* pooled = ws;                  // 2048*128   = 262144
    float* dec    = ws + 262144;         // 2048*512   = 1048576
    float* hist   = ws + 1310720;        // 256
    float* commit = ws + 1310976;        // 1

    hipMemsetAsync(hist, 0, 257 * sizeof(float), stream);

    k1_enc_pool<<<N_TOKENS, 128, 0, stream>>>(t0, t1, w1, b1, pooled);
    k2_mid<<<64, 256, 0, stream>>>(pooled, w2, b2, cb, dw1, db1, dw2, db2,
                                   dec, hist, commit, out + DECODED_SZ + 2);
    k2b_final<<<1, 256, 0, stream>>>(hist, commit, out + DECODED_SZ);
    k3_upsample<<<512, 256, 0, stream>>>(dec, out);
}

// Round 2
// 652.055 us; speedup vs baseline: 1.3404x; 1.3404x over previous
//
#include <hip/hip_runtime.h>
#include <math.h>

// B=512, H=W=14, DIN=512, EDIM=64, K=256, GRID=2 -> 2048 tokens, 128 hidden
#define N_TOKENS   2048
#define DECODED_SZ 51380224   // 512*14*14*512
// d_out layout: [decoded (51380224)][perplexity (1)][commitment (1)][indices (2048)]

__device__ __forceinline__ float gelu_exact(float x) {
    return 0.5f * x * (1.0f + erff(x * 0.70710678118654752440f));
}

// ---------------------------------------------------------------------------
// K1: pooled_h[b*4+tk][128] = mean_{49 pos} gelu(delta @ enc_w1 + b1)
// One block (512 thr = 8 waves) per IMAGE. 512 blocks = exactly 2/CU.
// K chunked by 32 into LDS (w1 16 KB + delta 196x36 = 27.6 KB -> 44.6 KB).
// Thread (g = t>>4 in [0,32), ng = t&15): token tk = g>>3, sub = g&7.
// TM=7 rows of token tk (sub*7+mm, clamped), TN=8 channels {4ng..+3, 64+4ng..+3}.
// ---------------------------------------------------------------------------
__global__ __launch_bounds__(512, 4) void k1_enc_pool(
    const float* __restrict__ t0, const float* __restrict__ t1,
    const float* __restrict__ w1, const float* __restrict__ b1,
    float* __restrict__ pooled)
{
    __shared__ float sW[32 * 128];     // w1 chunk [k][n], 16 KB
    __shared__ float sD[196 * 36];     // delta chunk [m][k], stride 36, 27.6 KB

    const int t  = threadIdx.x;
    const int b  = blockIdx.x;
    const int ng = t & 15;
    const int g  = t >> 4;          // 0..31
    const int tk = g >> 3;          // token 0..3
    const int sub = g & 7;          // 0..7 (sub==7 partly redundant, masked in epilogue)
    const int ty = tk >> 1, tx = tk & 1;

    const float4* __restrict__ w1v = reinterpret_cast<const float4*>(w1);
    const float4* __restrict__ t0v = reinterpret_cast<const float4*>(t0);
    const float4* __restrict__ t1v = reinterpret_cast<const float4*>(t1);

    // per-thread delta-row pointers (rows of this thread's token; clamped)
    const float* rowp[7];
#pragma unroll
    for (int mm = 0; mm < 7; ++mm) {
        int r = sub * 7 + mm;
        if (r > 48) r = 48;
        int m = (ty * 7 + r / 7) * 14 + tx * 7 + (r % 7);
        rowp[mm] = sD + m * 36;
    }

    float acc[7][8] = {};

    for (int kc = 0; kc < 16; ++kc) {
        // stage w1 chunk: 32x128 floats = 1024 float4
#pragma unroll
        for (int i = 0; i < 2; ++i) {
            int idx4 = t + i * 512;
            reinterpret_cast<float4*>(sW)[idx4] = w1v[kc * 1024 + idx4];
        }
        // stage delta chunk: 196 rows x 8 float4 = 1568 float4
        for (int i = t; i < 1568; i += 512) {
            int m = i >> 3, j = i & 7;
            int g4 = (b * 196 + m) * 128 + kc * 8 + j;
            float4 a = t1v[g4];
            float4 c = t0v[g4];
            float4 d;
            d.x = a.x - c.x; d.y = a.y - c.y; d.z = a.z - c.z; d.w = a.w - c.w;
            reinterpret_cast<float4*>(sD + m * 36)[j] = d;
        }
        __syncthreads();

        for (int kk = 0; kk < 32; kk += 2) {
            const float* wr0 = sW + kk * 128;
            const float* wr1 = wr0 + 128;
            const float4 wa0 = *reinterpret_cast<const float4*>(wr0 + 4 * ng);
            const float4 wb0 = *reinterpret_cast<const float4*>(wr0 + 64 + 4 * ng);
            const float4 wa1 = *reinterpret_cast<const float4*>(wr1 + 4 * ng);
            const float4 wb1 = *reinterpret_cast<const float4*>(wr1 + 64 + 4 * ng);
#pragma unroll
            for (int mm = 0; mm < 7; ++mm) {
                const float2 dv = *reinterpret_cast<const float2*>(rowp[mm] + kk);
                float* A = acc[mm];
                A[0] = fmaf(dv.x, wa0.x, A[0]);
                A[1] = fmaf(dv.x, wa0.y, A[1]);
                A[2] = fmaf(dv.x, wa0.z, A[2]);
                A[3] = fmaf(dv.x, wa0.w, A[3]);
                A[4] = fmaf(dv.x, wb0.x, A[4]);
                A[5] = fmaf(dv.x, wb0.y, A[5]);
                A[6] = fmaf(dv.x, wb0.z, A[6]);
                A[7] = fmaf(dv.x, wb0.w, A[7]);
                A[0] = fmaf(dv.y, wa1.x, A[0]);
                A[1] = fmaf(dv.y, wa1.y, A[1]);
                A[2] = fmaf(dv.y, wa1.z, A[2]);
                A[3] = fmaf(dv.y, wa1.w, A[3]);
                A[4] = fmaf(dv.y, wb1.x, A[4]);
                A[5] = fmaf(dv.y, wb1.y, A[5]);
                A[6] = fmaf(dv.y, wb1.z, A[6]);
                A[7] = fmaf(dv.y, wb1.w, A[7]);
            }
        }
        __syncthreads();
    }

    // epilogue: bias + gelu + partial pool over this thread's valid rows
    const float4 ba = *reinterpret_cast<const float4*>(b1 + 4 * ng);
    const float4 bb = *reinterpret_cast<const float4*>(b1 + 64 + 4 * ng);
    float p[8] = {};
#pragma unroll
    for (int mm = 0; mm < 7; ++mm) {
        int r = sub * 7 + mm;
        if (r < 49) {
            p[0] += gelu_exact(acc[mm][0] + ba.x);
            p[1] += gelu_exact(acc[mm][1] + ba.y);
            p[2] += gelu_exact(acc[mm][2] + ba.z);
            p[3] += gelu_exact(acc[mm][3] + ba.w);
            p[4] += gelu_exact(acc[mm][4] + bb.x);
            p[5] += gelu_exact(acc[mm][5] + bb.y);
            p[6] += gelu_exact(acc[mm][6] + bb.z);
            p[7] += gelu_exact(acc[mm][7] + bb.w);
        }
    }
    // reduce across the 8 sub-groups of each token (reuse sW: 32*128 = 4096 floats)
    float* sR = sW;
    {
        float4 pa; pa.x = p[0]; pa.y = p[1]; pa.z = p[2]; pa.w = p[3];
        float4 pb; pb.x = p[4]; pb.y = p[5]; pb.z = p[6]; pb.w = p[7];
        *reinterpret_cast<float4*>(sR + g * 128 + 4 * ng)      = pa;
        *reinterpret_cast<float4*>(sR + g * 128 + 64 + 4 * ng) = pb;
    }
    __syncthreads();
    {
        const int tk2 = t >> 7;      // token 0..3
        const int ch  = t & 127;
        float s = 0.f;
#pragma unroll
        for (int ss = 0; ss < 8; ++ss) s += sR[(tk2 * 8 + ss) * 128 + ch];
        pooled[(b * 4 + tk2) * 128 + ch] = s * (1.0f / 49.0f);
    }
}

// ---------------------------------------------------------------------------
// K2: per-token middle. 512 blocks x 256 thr, 4 tokens/block.
// Codebook staged in LDS (stride 66 -> conflict-free float2 reads).
// ---------------------------------------------------------------------------
__global__ __launch_bounds__(256, 2) void k2_mid(
    const float* __restrict__ pooled,
    const float* __restrict__ w2,  const float* __restrict__ b2,
    const float* __restrict__ cb,
    const float* __restrict__ dw1, const float* __restrict__ db1,
    const float* __restrict__ dw2, const float* __restrict__ db2,
    float* __restrict__ dec, float* __restrict__ hist, float* __restrict__ commit,
    float* __restrict__ out_idx)
{
    __shared__ float sCB[256 * 66];  // 67.6 KB codebook, padded stride
    __shared__ float ph[4 * 128];
    __shared__ float es[4 * 64];
    __shared__ float hd[4 * 128];
    __shared__ float rd[256];
    __shared__ int   ri[256];
    __shared__ int   idxs[4];
    __shared__ float dms[4];

    const int t   = threadIdx.x;
    const int tk0 = blockIdx.x * 4;

    if (t < 128)
        reinterpret_cast<float4*>(ph)[t] =
            reinterpret_cast<const float4*>(pooled + tk0 * 128)[t];
    for (int i = t; i < 16384; i += 256) {
        int row = i >> 6, k = i & 63;
        sCB[row * 66 + k] = cb[i];
    }
    __syncthreads();

    // e = ph @ w2 + b2   (j = t&63, one token per 64-lane group)
    {
        const int j = t & 63, tok = t >> 6;
        float a = b2[j];
        const float* phr = ph + tok * 128;
#pragma unroll 8
        for (int k = 0; k < 128; ++k)
            a = fmaf(phr[k], w2[k * 64 + j], a);
        es[tok * 64 + j] = a;
    }
    __syncthreads();

    // VQ: 64 threads/token, 4 strided codes each; explicit index tiebreak
    {
        const int tok = t >> 6, c8 = t & 63;
        float2 ev[32];
#pragma unroll
        for (int k = 0; k < 32; ++k)
            ev[k] = *reinterpret_cast<const float2*>(es + tok * 64 + 2 * k);
        float dmin = 3.4e38f; int imin = 0;
#pragma unroll
        for (int cc = 0; cc < 4; ++cc) {
            const int c = c8 + cc * 64;
            const float* cr = sCB + c * 66;
            float d = 0.f;
#pragma unroll
            for (int k = 0; k < 32; ++k) {
                float2 c2 = *reinterpret_cast<const float2*>(cr + 2 * k);
                float d0 = ev[k].x - c2.x;
                float d1 = ev[k].y - c2.y;
                d = fmaf(d0, d0, d);
                d = fmaf(d1, d1, d);
            }
            if (d < dmin || (d == dmin && c < imin)) { dmin = d; imin = c; }
        }
        rd[t] = dmin; ri[t] = imin;
    }
    __syncthreads();
    for (int s = 32; s > 0; s >>= 1) {
        if ((t & 63) < s) {
            float dn = rd[t + s]; int in = ri[t + s];
            if (dn < rd[t] || (dn == rd[t] && in < ri[t])) { rd[t] = dn; ri[t] = in; }
        }
        __syncthreads();
    }
    if ((t & 63) == 0) {
        const int tok = t >> 6;
        idxs[tok] = ri[t];
        dms[tok]  = rd[t];
        out_idx[tk0 + tok] = (float)ri[t];
        atomicAdd(&hist[ri[t]], 1.0f);
    }
    __syncthreads();
    if (t == 0) {
        float s = dms[0] + dms[1] + dms[2] + dms[3];
        atomicAdd(commit, s);
    }

    // hd = gelu(q @ dw1 + db1), q read straight from sCB
    {
        const int j = t & 127, half = t >> 7;
        const float bj = db1[j];
        float a0 = bj, a1 = bj;
        const float* q0 = sCB + idxs[half * 2 + 0] * 66;
        const float* q1 = sCB + idxs[half * 2 + 1] * 66;
#pragma unroll 4
        for (int k = 0; k < 64; ++k) {
            const float wv = dw1[k * 128 + j];
            a0 = fmaf(q0[k], wv, a0);
            a1 = fmaf(q1[k], wv, a1);
        }
        hd[(half * 2 + 0) * 128 + j] = gelu_exact(a0);
        hd[(half * 2 + 1) * 128 + j] = gelu_exact(a1);
    }
    __syncthreads();

    // dec = hd @ dw2 + db2  (each thread: cols t and t+256, all 4 tokens)
    {
        float a0[4], a1[4];
        const float bb0 = db2[t], bb1 = db2[t + 256];
#pragma unroll
        for (int q = 0; q < 4; ++q) { a0[q] = bb0; a1[q] = bb1; }
#pragma unroll 2
        for (int j = 0; j < 128; ++j) {
            const float w0 = dw2[j * 512 + t];
            const float w1v = dw2[j * 512 + 256 + t];
#pragma unroll
            for (int q = 0; q < 4; ++q) {
                const float h = hd[q * 128 + j];
                a0[q] = fmaf(h, w0, a0[q]);
                a1[q] = fmaf(h, w1v, a1[q]);
            }
        }
#pragma unroll
        for (int q = 0; q < 4; ++q) {
            dec[(tk0 + q) * 512 + t]       = a0[q];
            dec[(tk0 + q) * 512 + 256 + t] = a1[q];
        }
    }
}

// ---------------------------------------------------------------------------
// K2b: finalize perplexity + commitment (1 block)
// ---------------------------------------------------------------------------
__global__ __launch_bounds__(256) void k2b_final(
    const float* __restrict__ hist, const float* __restrict__ commit,
    float* __restrict__ out2)
{
    __shared__ float red[256];
    const int t = threadIdx.x;
    float p = hist[t] * (1.0f / 2048.0f);
    red[t] = p * logf(p + 1e-10f);
    __syncthreads();
    for (int s = 128; s > 0; s >>= 1) {
        if (t < s) red[t] += red[t + s];
        __syncthreads();
    }
    if (t == 0) {
        out2[0] = expf(-red[0]);
        out2[1] = commit[0] * (1.0f / 131072.0f);   // /(2048*64)
    }
}

// ---------------------------------------------------------------------------
// K3: bilinear upsample dec[B,2,2,512] -> decoded[B,14,14,512]
// Weights/offsets precomputed once per block into LDS.
// ---------------------------------------------------------------------------
__global__ __launch_bounds__(256, 4) void k3_upsample(
    const float* __restrict__ dec, float* __restrict__ out)
{
    __shared__ float  sdec[4 * 512];
    __shared__ float4 wts[196];
    __shared__ int4   offs[196];
    const int b = blockIdx.x, t = threadIdx.x;

    for (int i = t; i < 512; i += 256)
        reinterpret_cast<float4*>(sdec)[i] =
            reinterpret_cast<const float4*>(dec + b * 2048)[i];
    if (t < 196) {
        const int y = t / 14, x = t % 14;
        const float sy = (y + 0.5f) * (1.0f / 7.0f) - 0.5f;
        const float sx = (x + 0.5f) * (1.0f / 7.0f) - 0.5f;
        const int iy = (int)floorf(sy), ix = (int)floorf(sx);
        const float fy = sy - (float)iy, fx = sx - (float)ix;
        const int y0 = min(max(iy, 0), 1), y1 = min(max(iy + 1, 0), 1);
        const int x0 = min(max(ix, 0), 1), x1 = min(max(ix + 1, 0), 1);
        float4 w;
        w.x = (1.f - fy) * (1.f - fx); w.y = (1.f - fy) * fx;
        w.z = fy * (1.f - fx);         w.w = fy * fx;
        wts[t] = w;
        int4 o;
        o.x = (y0 * 2 + x0) * 128; o.y = (y0 * 2 + x1) * 128;
        o.z = (y1 * 2 + x0) * 128; o.w = (y1 * 2 + x1) * 128;
        offs[t] = o;
    }
    __syncthreads();

    const float4* s4 = reinterpret_cast<const float4*>(sdec);
    float4* o4 = reinterpret_cast<float4*>(out) + b * 25088;
    const int c4 = t & 127, ph2 = t >> 7;

#pragma unroll 2
    for (int it = 0; it < 98; ++it) {
        const int pos = ph2 + it * 2;
        const float4 w = wts[pos];
        const int4   o = offs[pos];
        const float4 v00 = s4[o.x + c4];
        const float4 v01 = s4[o.y + c4];
        const float4 v10 = s4[o.z + c4];
        const float4 v11 = s4[o.w + c4];
        float4 r;
        r.x = w.x * v00.x + w.y * v01.x + w.z * v10.x + w.w * v11.x;
        r.y = w.x * v00.y + w.y * v01.y + w.z * v10.y + w.w * v11.y;
        r.z = w.x * v00.z + w.y * v01.z + w.z * v10.z + w.w * v11.z;
        r.w = w.x * v00.w + w.y * v01.w + w.z * v10.w + w.w * v11.w;
        o4[pos * 128 + c4] = r;
    }
}

// ---------------------------------------------------------------------------
extern "C" void kernel_launch(void* const* d_in, const int* in_sizes, int n_in,
                              void* d_out, int out_size, void* d_ws, size_t ws_size,
                              hipStream_t stream)
{
    const float* t0  = (const float*)d_in[0];
    const float* t1  = (const float*)d_in[1];
    const float* w1  = (const float*)d_in[2];
    const float* b1  = (const float*)d_in[3];
    const float* w2  = (const float*)d_in[4];
    const float* b2  = (const float*)d_in[5];
    const float* dw1 = (const float*)d_in[6];
    const float* db1 = (const float*)d_in[7];
    const float* dw2 = (const float*)d_in[8];
    const float* db2 = (const float*)d_in[9];
    const float* cb  = (const float*)d_in[10];

    float* out = (float*)d_out;
    float* ws  = (float*)d_ws;

    float* pooled = ws;                  // 2048*128   = 262144
    float* dec    = ws + 262144;         // 2048*512   = 1048576
    float* hist   = ws + 1310720;        // 256
    float* commit = ws + 1310976;        // 1

    hipMemsetAsync(hist, 0, 257 * sizeof(float), stream);

    k1_enc_pool<<<512, 512, 0, stream>>>(t0, t1, w1, b1, pooled);
    k2_mid<<<512, 256, 0, stream>>>(pooled, w2, b2, cb, dw1, db1, dw2, db2,
                                    dec, hist, commit, out + DECODED_SZ + 2);
    k2b_final<<<1, 256, 0, stream>>>(hist, commit, out + DECODED_SZ);
    k3_upsample<<<512, 256, 0, stream>>>(dec, out);
}

// Round 3
// 648.580 us; speedup vs baseline: 1.3476x; 1.0054x over previous
//
#include <hip/hip_runtime.h>
#include <math.h>

// B=512, H=W=14, DIN=512, EDIM=64, K=256, GRID=2 -> 2048 tokens, 128 hidden
#define N_TOKENS   2048
#define DECODED_SZ 51380224   // 512*14*14*512
// d_out layout: [decoded (51380224)][perplexity (1)][commitment (1)][indices (2048)]

typedef __attribute__((ext_vector_type(8)))  short bf16x8;
typedef __attribute__((ext_vector_type(16))) float f32x16;

__device__ __forceinline__ float gelu_exact(float x) {
    return 0.5f * x * (1.0f + erff(x * 0.70710678118654752440f));
}

// round-to-nearest-even fp32 -> bf16 bits
__device__ __forceinline__ unsigned int f2bf(float x) {
    unsigned int u = __float_as_uint(x);
    return (u + 0x7fffu + ((u >> 16) & 1u)) >> 16;
}
__device__ __forceinline__ float bf2f(unsigned int b) {
    return __uint_as_float(b << 16);
}

// ---------------------------------------------------------------------------
// K0: split w1 [512k x 128n] fp32 into bf16 hi/lo, transposed + k-chunk-blocked
// for direct B-fragment staging: Bt[kc(16)][n(128)][k(32)] bf16.
// 8192 threads: i = n*64 + kg8 (kg8 = group of 8 consecutive k).
// ---------------------------------------------------------------------------
__global__ __launch_bounds__(256) void k0_prep_w1(
    const float* __restrict__ w1,
    unsigned short* __restrict__ bth, unsigned short* __restrict__ btl)
{
    const int i  = blockIdx.x * 256 + threadIdx.x;   // 0..8191
    const int n  = i >> 6;
    const int kg = i & 63;
    const int k0i = kg * 8;

    unsigned int h[8], lo[8];
#pragma unroll
    for (int j = 0; j < 8; ++j) {
        float v = w1[(k0i + j) * 128 + n];
        h[j]  = f2bf(v);
        lo[j] = f2bf(v - bf2f(h[j]));
    }
    const int idx = (k0i >> 5) * 4096 + n * 32 + (k0i & 31);
    uint4 hv, lv;
    hv.x = h[0]  | (h[1] << 16);  hv.y = h[2]  | (h[3] << 16);
    hv.z = h[4]  | (h[5] << 16);  hv.w = h[6]  | (h[7] << 16);
    lv.x = lo[0] | (lo[1] << 16); lv.y = lo[2] | (lo[3] << 16);
    lv.z = lo[4] | (lo[5] << 16); lv.w = lo[6] | (lo[7] << 16);
    *reinterpret_cast<uint4*>(bth + idx) = hv;
    *reinterpret_cast<uint4*>(btl + idx) = lv;
}

// ---------------------------------------------------------------------------
// K1: pooled_h[b*4+tk][128] = mean_{49 pos} gelu(delta @ enc_w1 + b1)
// MFMA split-bf16: D = Ah*Bh + Ah*Bl + Al*Bh (fp32 acc).
// One block per image, 256 thr = 4 waves, 2 blocks/CU.
// M padded 196->256 (8 tiles of 32), N=128 (4 tiles), K=512 chunked by 32.
// Wave (wm = w>>1, wn = w&1): M-tiles [wm*4, +4), N-tiles [wn*2, +2).
// LDS: A hi/lo [256][32+8pad] + B hi/lo [128][32+8pad] + reduce = 64 KB.
// ---------------------------------------------------------------------------
__global__ __launch_bounds__(256, 2) void k1_enc_pool(
    const float* __restrict__ t0, const float* __restrict__ t1,
    const unsigned short* __restrict__ bth, const unsigned short* __restrict__ btl,
    const float* __restrict__ b1,
    float* __restrict__ pooled)
{
    __shared__ unsigned short sAh[256 * 40];   // 20 KB
    __shared__ unsigned short sAl[256 * 40];   // 20 KB
    __shared__ unsigned short sBh[128 * 40];   // 10 KB
    __shared__ unsigned short sBl[128 * 40];   // 10 KB
    __shared__ float sR[2 * 4 * 128];          // 4 KB  (wm, tok, col)

    const int t = threadIdx.x;
    const int b = blockIdx.x;
    const int l     = t & 63;
    const int w     = t >> 6;
    const int wm    = w >> 1;
    const int wn    = w & 1;
    const int lan31 = l & 31;
    const int h     = l >> 5;

    const float4* __restrict__ t0v = reinterpret_cast<const float4*>(t0);
    const float4* __restrict__ t1v = reinterpret_cast<const float4*>(t1);

    f32x16 acc[4][2] = {};

    for (int kc = 0; kc < 16; ++kc) {
        __syncthreads();   // protect LDS from overwrite while prior compute reads
        // ---- stage A chunk: rows 0..195, k in [kc*32, +32), fp32 -> hi/lo bf16
        for (int i = t; i < 196 * 8; i += 256) {
            const int m = i >> 3, j = i & 7;   // j: float4 within the 32-k chunk
            const int g4 = (b * 196 + m) * 128 + kc * 8 + j;
            const float4 a = t1v[g4];
            const float4 c = t0v[g4];
            const float dx = a.x - c.x, dy = a.y - c.y, dz = a.z - c.z, dw = a.w - c.w;
            const unsigned int h0 = f2bf(dx), h1 = f2bf(dy), h2 = f2bf(dz), h3 = f2bf(dw);
            const unsigned int l0 = f2bf(dx - bf2f(h0)), l1 = f2bf(dy - bf2f(h1));
            const unsigned int l2 = f2bf(dz - bf2f(h2)), l3 = f2bf(dw - bf2f(h3));
            uint2 hv, lv;
            hv.x = h0 | (h1 << 16); hv.y = h2 | (h3 << 16);
            lv.x = l0 | (l1 << 16); lv.y = l2 | (l3 << 16);
            *reinterpret_cast<uint2*>(&sAh[m * 40 + j * 4]) = hv;
            *reinterpret_cast<uint2*>(&sAl[m * 40 + j * 4]) = lv;
        }
        // ---- stage B chunk from prepped Bt: [kc][128][32]
        for (int i = t; i < 1024; i += 256) {
            const int sel = i >> 9;
            const int i2 = i & 511;
            const int col = i2 >> 2, j8 = i2 & 3;
            const uint4 v = *reinterpret_cast<const uint4*>(
                (sel ? btl : bth) + kc * 4096 + col * 32 + j8 * 8);
            *reinterpret_cast<uint4*>(&(sel ? sBl : sBh)[col * 40 + j8 * 8]) = v;
        }
        __syncthreads();

        // ---- compute: 2 K-steps of 16
#pragma unroll
        for (int ks = 0; ks < 2; ++ks) {
            const int koff = ks * 16 + h * 8;
            bf16x8 ah[4], al[4], bhf[2], blf[2];
#pragma unroll
            for (int mi = 0; mi < 4; ++mi) {
                const int row = (wm * 4 + mi) * 32 + lan31;
                ah[mi] = *reinterpret_cast<const bf16x8*>(&sAh[row * 40 + koff]);
                al[mi] = *reinterpret_cast<const bf16x8*>(&sAl[row * 40 + koff]);
            }
#pragma unroll
            for (int ni = 0; ni < 2; ++ni) {
                const int col = (wn * 2 + ni) * 32 + lan31;
                bhf[ni] = *reinterpret_cast<const bf16x8*>(&sBh[col * 40 + koff]);
                blf[ni] = *reinterpret_cast<const bf16x8*>(&sBl[col * 40 + koff]);
            }
#pragma unroll
            for (int mi = 0; mi < 4; ++mi) {
#pragma unroll
                for (int ni = 0; ni < 2; ++ni) {
                    acc[mi][ni] = __builtin_amdgcn_mfma_f32_32x32x16_bf16(
                        ah[mi], bhf[ni], acc[mi][ni], 0, 0, 0);
                    acc[mi][ni] = __builtin_amdgcn_mfma_f32_32x32x16_bf16(
                        ah[mi], blf[ni], acc[mi][ni], 0, 0, 0);
                    acc[mi][ni] = __builtin_amdgcn_mfma_f32_32x32x16_bf16(
                        al[mi], bhf[ni], acc[mi][ni], 0, 0, 0);
                }
            }
        }
    }

    // ---- epilogue: bias + gelu + pool per token, per lane
    float tokacc[2][4] = {};
#pragma unroll
    for (int ni = 0; ni < 2; ++ni) {
        const int col = (wn * 2 + ni) * 32 + lan31;
        const float bias = b1[col];
#pragma unroll
        for (int mi = 0; mi < 4; ++mi) {
#pragma unroll
            for (int reg = 0; reg < 16; ++reg) {
                const int row = (wm * 4 + mi) * 32 + (reg & 3) + 8 * (reg >> 2) + 4 * h;
                if (row < 196) {
                    const float v = gelu_exact(acc[mi][ni][reg] + bias);
                    const int py = row / 14, px = row % 14;
                    const int tok = ((py >= 7) ? 2 : 0) + ((px >= 7) ? 1 : 0);
                    tokacc[ni][tok] += v;
                }
            }
        }
    }
    // fold h=1 lanes into h=0 lanes
#pragma unroll
    for (int ni = 0; ni < 2; ++ni)
#pragma unroll
        for (int tok = 0; tok < 4; ++tok)
            tokacc[ni][tok] += __shfl_xor(tokacc[ni][tok], 32);
    if (h == 0) {
#pragma unroll
        for (int ni = 0; ni < 2; ++ni)
#pragma unroll
            for (int tok = 0; tok < 4; ++tok)
                sR[(wm * 4 + tok) * 128 + wn * 64 + ni * 32 + lan31] = tokacc[ni][tok];
    }
    __syncthreads();
    for (int i = t; i < 512; i += 256) {
        const int tok = i >> 7, col = i & 127;
        pooled[(b * 4 + tok) * 128 + col] =
            (sR[tok * 128 + col] + sR[(4 + tok) * 128 + col]) * (1.0f / 49.0f);
    }
}

// ---------------------------------------------------------------------------
// K2: per-token middle. 512 blocks x 256 thr, 4 tokens/block.
// Codebook staged in LDS (stride 66 -> conflict-free float2 reads).
// ---------------------------------------------------------------------------
__global__ __launch_bounds__(256, 2) void k2_mid(
    const float* __restrict__ pooled,
    const float* __restrict__ w2,  const float* __restrict__ b2,
    const float* __restrict__ cb,
    const float* __restrict__ dw1, const float* __restrict__ db1,
    const float* __restrict__ dw2, const float* __restrict__ db2,
    float* __restrict__ dec, float* __restrict__ hist, float* __restrict__ commit,
    float* __restrict__ out_idx)
{
    __shared__ float sCB[256 * 66];  // 67.6 KB codebook, padded stride
    __shared__ float ph[4 * 128];
    __shared__ float es[4 * 64];
    __shared__ float hd[4 * 128];
    __shared__ float rd[256];
    __shared__ int   ri[256];
    __shared__ int   idxs[4];
    __shared__ float dms[4];

    const int t   = threadIdx.x;
    const int tk0 = blockIdx.x * 4;

    if (t < 128)
        reinterpret_cast<float4*>(ph)[t] =
            reinterpret_cast<const float4*>(pooled + tk0 * 128)[t];
    for (int i = t; i < 16384; i += 256) {
        int row = i >> 6, k = i & 63;
        sCB[row * 66 + k] = cb[i];
    }
    __syncthreads();

    // e = ph @ w2 + b2   (j = t&63, one token per 64-lane group)
    {
        const int j = t & 63, tok = t >> 6;
        float a = b2[j];
        const float* phr = ph + tok * 128;
#pragma unroll 8
        for (int k = 0; k < 128; ++k)
            a = fmaf(phr[k], w2[k * 64 + j], a);
        es[tok * 64 + j] = a;
    }
    __syncthreads();

    // VQ: 64 threads/token, 4 strided codes each; explicit index tiebreak
    {
        const int tok = t >> 6, c8 = t & 63;
        float2 ev[32];
#pragma unroll
        for (int k = 0; k < 32; ++k)
            ev[k] = *reinterpret_cast<const float2*>(es + tok * 64 + 2 * k);
        float dmin = 3.4e38f; int imin = 0;
#pragma unroll
        for (int cc = 0; cc < 4; ++cc) {
            const int c = c8 + cc * 64;
            const float* cr = sCB + c * 66;
            float d = 0.f;
#pragma unroll
            for (int k = 0; k < 32; ++k) {
                float2 c2 = *reinterpret_cast<const float2*>(cr + 2 * k);
                float d0 = ev[k].x - c2.x;
                float d1 = ev[k].y - c2.y;
                d = fmaf(d0, d0, d);
                d = fmaf(d1, d1, d);
            }
            if (d < dmin || (d == dmin && c < imin)) { dmin = d; imin = c; }
        }
        rd[t] = dmin; ri[t] = imin;
    }
    __syncthreads();
    for (int s = 32; s > 0; s >>= 1) {
        if ((t & 63) < s) {
            float dn = rd[t + s]; int in = ri[t + s];
            if (dn < rd[t] || (dn == rd[t] && in < ri[t])) { rd[t] = dn; ri[t] = in; }
        }
        __syncthreads();
    }
    if ((t & 63) == 0) {
        const int tok = t >> 6;
        idxs[tok] = ri[t];
        dms[tok]  = rd[t];
        out_idx[tk0 + tok] = (float)ri[t];
        atomicAdd(&hist[ri[t]], 1.0f);
    }
    __syncthreads();
    if (t == 0) {
        float s = dms[0] + dms[1] + dms[2] + dms[3];
        atomicAdd(commit, s);
    }

    // hd = gelu(q @ dw1 + db1), q read straight from sCB
    {
        const int j = t & 127, half = t >> 7;
        const float bj = db1[j];
        float a0 = bj, a1 = bj;
        const float* q0 = sCB + idxs[half * 2 + 0] * 66;
        const float* q1 = sCB + idxs[half * 2 + 1] * 66;
#pragma unroll 4
        for (int k = 0; k < 64; ++k) {
            const float wv = dw1[k * 128 + j];
            a0 = fmaf(q0[k], wv, a0);
            a1 = fmaf(q1[k], wv, a1);
        }
        hd[(half * 2 + 0) * 128 + j] = gelu_exact(a0);
        hd[(half * 2 + 1) * 128 + j] = gelu_exact(a1);
    }
    __syncthreads();

    // dec = hd @ dw2 + db2  (each thread: cols t and t+256, all 4 tokens)
    {
        float a0[4], a1[4];
        const float bb0 = db2[t], bb1 = db2[t + 256];
#pragma unroll
        for (int q = 0; q < 4; ++q) { a0[q] = bb0; a1[q] = bb1; }
#pragma unroll 2
        for (int j = 0; j < 128; ++j) {
            const float w0 = dw2[j * 512 + t];
            const float w1v = dw2[j * 512 + 256 + t];
#pragma unroll
            for (int q = 0; q < 4; ++q) {
                const float h = hd[q * 128 + j];
                a0[q] = fmaf(h, w0, a0[q]);
                a1[q] = fmaf(h, w1v, a1[q]);
            }
        }
#pragma unroll
        for (int q = 0; q < 4; ++q) {
            dec[(tk0 + q) * 512 + t]       = a0[q];
            dec[(tk0 + q) * 512 + 256 + t] = a1[q];
        }
    }
}

// ---------------------------------------------------------------------------
// K2b: finalize perplexity + commitment (1 block)
// ---------------------------------------------------------------------------
__global__ __launch_bounds__(256) void k2b_final(
    const float* __restrict__ hist, const float* __restrict__ commit,
    float* __restrict__ out2)
{
    __shared__ float red[256];
    const int t = threadIdx.x;
    float p = hist[t] * (1.0f / 2048.0f);
    red[t] = p * logf(p + 1e-10f);
    __syncthreads();
    for (int s = 128; s > 0; s >>= 1) {
        if (t < s) red[t] += red[t + s];
        __syncthreads();
    }
    if (t == 0) {
        out2[0] = expf(-red[0]);
        out2[1] = commit[0] * (1.0f / 131072.0f);   // /(2048*64)
    }
}

// ---------------------------------------------------------------------------
// K3: bilinear upsample dec[B,2,2,512] -> decoded[B,14,14,512]
// Weights/offsets precomputed once per block into LDS.
// ---------------------------------------------------------------------------
__global__ __launch_bounds__(256, 4) void k3_upsample(
    const float* __restrict__ dec, float* __restrict__ out)
{
    __shared__ float  sdec[4 * 512];
    __shared__ float4 wts[196];
    __shared__ int4   offs[196];
    const int b = blockIdx.x, t = threadIdx.x;

    for (int i = t; i < 512; i += 256)
        reinterpret_cast<float4*>(sdec)[i] =
            reinterpret_cast<const float4*>(dec + b * 2048)[i];
    if (t < 196) {
        const int y = t / 14, x = t % 14;
        const float sy = (y + 0.5f) * (1.0f / 7.0f) - 0.5f;
        const float sx = (x + 0.5f) * (1.0f / 7.0f) - 0.5f;
        const int iy = (int)floorf(sy), ix = (int)floorf(sx);
        const float fy = sy - (float)iy, fx = sx - (float)ix;
        const int y0 = min(max(iy, 0), 1), y1 = min(max(iy + 1, 0), 1);
        const int x0 = min(max(ix, 0), 1), x1 = min(max(ix + 1, 0), 1);
        float4 w;
        w.x = (1.f - fy) * (1.f - fx); w.y = (1.f - fy) * fx;
        w.z = fy * (1.f - fx);         w.w = fy * fx;
        wts[t] = w;
        int4 o;
        o.x = (y0 * 2 + x0) * 128; o.y = (y0 * 2 + x1) * 128;
        o.z = (y1 * 2 + x0) * 128; o.w = (y1 * 2 + x1) * 128;
        offs[t] = o;
    }
    __syncthreads();

    const float4* s4 = reinterpret_cast<const float4*>(sdec);
    float4* o4 = reinterpret_cast<float4*>(out) + b * 25088;
    const int c4 = t & 127, ph2 = t >> 7;

#pragma unroll 2
    for (int it = 0; it < 98; ++it) {
        const int pos = ph2 + it * 2;
        const float4 w = wts[pos];
        const int4   o = offs[pos];
        const float4 v00 = s4[o.x + c4];
        const float4 v01 = s4[o.y + c4];
        const float4 v10 = s4[o.z + c4];
        const float4 v11 = s4[o.w + c4];
        float4 r;
        r.x = w.x * v00.x + w.y * v01.x + w.z * v10.x + w.w * v11.x;
        r.y = w.x * v00.y + w.y * v01.y + w.z * v10.y + w.w * v11.y;
        r.z = w.x * v00.z + w.y * v01.z + w.z * v10.z + w.w * v11.z;
        r.w = w.x * v00.w + w.y * v01.w + w.z * v10.w + w.w * v11.w;
        o4[pos * 128 + c4] = r;
    }
}

// ---------------------------------------------------------------------------
extern "C" void kernel_launch(void* const* d_in, const int* in_sizes, int n_in,
                              void* d_out, int out_size, void* d_ws, size_t ws_size,
                              hipStream_t stream)
{
    const float* t0  = (const float*)d_in[0];
    const float* t1  = (const float*)d_in[1];
    const float* w1  = (const float*)d_in[2];
    const float* b1  = (const float*)d_in[3];
    const float* w2  = (const float*)d_in[4];
    const float* b2  = (const float*)d_in[5];
    const float* dw1 = (const float*)d_in[6];
    const float* db1 = (const float*)d_in[7];
    const float* dw2 = (const float*)d_in[8];
    const float* db2 = (const float*)d_in[9];
    const float* cb  = (const float*)d_in[10];

    float* out = (float*)d_out;
    float* ws  = (float*)d_ws;

    float* pooled = ws;                  // 2048*128   = 262144 floats
    float* dec    = ws + 262144;         // 2048*512   = 1048576 floats
    float* hist   = ws + 1310720;        // 256
    float* commit = ws + 1310976;        // 1

    // Bt hi/lo (bf16, 64K elems each) alias the dec region: k0/k1 finish
    // before k2 writes dec.
    unsigned short* bth = (unsigned short*)(ws + 262144);
    unsigned short* btl = (unsigned short*)(ws + 262144 + 32768);

    hipMemsetAsync(hist, 0, 257 * sizeof(float), stream);

    k0_prep_w1<<<32, 256, 0, stream>>>(w1, bth, btl);
    k1_enc_pool<<<512, 256, 0, stream>>>(t0, t1, bth, btl, b1, pooled);
    k2_mid<<<512, 256, 0, stream>>>(pooled, w2, b2, cb, dw1, db1, dw2, db2,
                                    dec, hist, commit, out + DECODED_SZ + 2);
    k2b_final<<<1, 256, 0, stream>>>(hist, commit, out + DECODED_SZ);
    k3_upsample<<<512, 256, 0, stream>>>(dec, out);
}